// Round 12
// baseline (59.464 us; speedup 1.0000x reference)
//
#include <hip/hip_runtime.h>

#define GAMMA 0.7f
static constexpr int K = 8;
static constexpr int B = 512;       // threads per block
static constexpr int P = B * 4;     // atoms per block (4 per thread)
static constexpr int NW = B / 64;   // waves per block

// Fixed-point scale for deterministic integer atomic accumulation.
static constexpr float SCALE     = 16777216.0f;        // 2^24
static constexpr float INV_SCALE = 1.0f / 16777216.0f;

// ---------------------------------------------------------------------------
// SINGLE streaming kernel (+ one 128B memset node). molecule_id is SORTED.
// Per-atom counts from the block's LDS window (interleaved dual binary
// search); block-edge runs resolved cooperatively (wave0/last wave + ballot).
// Cross-block reduction WITHOUT a second kernel and WITHOUT device fences
// (R2 lesson): each block atomicAdds int64 fixed-point partials into K global
// cells (integer adds = order-independent = deterministic); completion is
// enforced by consuming the atomics' return values + s_waitcnt vmcnt(0)
// before the done-counter increment; the last block reads the cells back
// with coherent atomic reads and writes the scalar. No spinning.
// ws: [0,64) K int64 cells | [64,68) vcount | [68,72) done ctr  (memset/call)
// ---------------------------------------------------------------------------

__global__ void __launch_bounds__(B)
main_fused(const float* __restrict__ sx,      // (K, N, 3)
           const float* __restrict__ xt,      // (N, 3)
           const int* __restrict__ mol,       // (N,) sorted
           unsigned long long* __restrict__ cells,  // (K,)
           int* __restrict__ vcount,
           unsigned* __restrict__ ctr,
           float* __restrict__ out,
           int N, int nblocks) {
    const int tid = threadIdx.x;
    const int b0  = blockIdx.x * P;
    const int n0  = b0 + tid * 4;

    // ids[0] = mol[b0-1] (or -1), ids[1..P] = window (INT_MAX past N),
    // ids[P+1] = mol[b0+P] (or INT_MAX). Real ids are in [0, M).
    __shared__ int ids[P + 2];
    __shared__ int edgeLR[2];
    int* w = ids + 1;

    int myid[4];
    if (n0 + 3 < N) {
        int4 v = *reinterpret_cast<const int4*>(mol + n0);
        myid[0] = v.x; myid[1] = v.y; myid[2] = v.z; myid[3] = v.w;
    } else {
#pragma unroll
        for (int j = 0; j < 4; ++j) {
            int n = n0 + j;
            myid[j] = (n < N) ? mol[n] : 0x7fffffff;
        }
    }
#pragma unroll
    for (int j = 0; j < 4; ++j) w[tid * 4 + j] = myid[j];
    if (tid == 0) {
        ids[0]    = (b0 == 0) ? -1 : mol[b0 - 1];
        edgeLR[0] = b0;
        edgeLR[1] = b0 + P;
    }
    if (tid == B - 1) ids[P + 1] = (b0 + P >= N) ? 0x7fffffff : mol[b0 + P];
    __syncthreads();

    const int wave = tid >> 6, lane = tid & 63;

    // ---- cooperative block-edge searches (wave 0 left, last wave right) ----
    if (wave == 0) {
        if (b0 > 0 && ids[0] == w[0]) {        // run extends left of block
            const int id = w[0];               // mol[b0-1] == id
            int c = 0;
            for (;;) {
                int idx = b0 - 1 - (c * 64 + lane);
                bool ended = (idx < 0) || (mol[idx] != id);
                unsigned long long m = __ballot(ended);
                if (m) {
                    if (lane == 0) {
                        int l0 = __ffsll((long long)m) - 1;
                        edgeLR[0] = b0 - 1 - (c * 64 + l0) + 1;
                    }
                    break;
                }
                ++c;
            }
        }
    } else if (wave == NW - 1) {
        if (b0 + P < N && ids[P + 1] == w[P - 1]) {  // run extends right
            const int id = w[P - 1];                 // mol[b0+P] == id
            int c = 0;
            for (;;) {
                int idx = b0 + P + (c * 64 + lane);
                bool ended = (idx >= N) || (mol[idx] != id);
                unsigned long long m = __ballot(ended);
                if (m) {
                    if (lane == 0) {
                        int l0 = __ffsll((long long)m) - 1;
                        edgeLR[1] = b0 + P + (c * 64 + l0);
                    }
                    break;
                }
                ++c;
            }
        }
    }

    // ---- local run extents (interleaved dual LDS search); validity count ----
    int sj[4], ej[4];
    int nb = 0;
#pragma unroll
    for (int j = 0; j < 4; ++j) {
        const int p  = tid * 4 + j;
        const int id = myid[j];
        const bool valid = (b0 + p < N);
        const int prevv = (j > 0) ? myid[j - 1] : ids[p];  // ids[p] == w[p-1]
        if (valid && prevv != id) ++nb;
        if (j > 0 && myid[j - 1] == id) { sj[j] = sj[j - 1]; ej[j] = ej[j - 1]; continue; }
        if (!valid) { sj[j] = 0; ej[j] = 1; continue; }  // dummy, inv unused

        int slo = 0, shi = p, elo = p + 1, ehi = P;
        while (slo < shi || elo < ehi) {
            if (slo < shi) {
                int m = (slo + shi) >> 1;
                if (w[m] < id) slo = m + 1; else shi = m;
            }
            if (elo < ehi) {
                int m = (elo + ehi) >> 1;
                if (w[m] <= id) elo = m + 1; else ehi = m;
            }
        }
        sj[j] = slo; ej[j] = elo;
    }
    __syncthreads();  // edgeLR ready

    const int eL = edgeLR[0], eR = edgeLR[1];
    float inv[4];
#pragma unroll
    for (int j = 0; j < 4; ++j) {
        const bool valid = (b0 + tid * 4 + j < N);
        const int gstart = (sj[j] == 0) ? eL : b0 + sj[j];
        const int gend   = (ej[j] == P) ? eR : b0 + ej[j];
        inv[j] = valid ? 1.0f / (float)(gend - gstart) : 0.0f;
    }

    // ---- stream states, accumulate sq * inv (known-good 4-atom body) ----
    float acc[K];
#pragma unroll
    for (int k = 0; k < K; ++k) acc[k] = 0.0f;

    if (n0 + 3 < N) {
        const float4* tp = reinterpret_cast<const float4*>(xt + (size_t)n0 * 3);
        float4 t0 = tp[0], t1 = tp[1], t2 = tp[2];
        float tg[12] = {t0.x, t0.y, t0.z, t0.w, t1.x, t1.y,
                        t1.z, t1.w, t2.x, t2.y, t2.z, t2.w};
#pragma unroll
        for (int k = 0; k < K; ++k) {
            const float4* sp = reinterpret_cast<const float4*>(
                sx + (size_t)k * N * 3 + (size_t)n0 * 3);
            float4 s0 = sp[0], s1 = sp[1], s2 = sp[2];
            float sv[12] = {s0.x, s0.y, s0.z, s0.w, s1.x, s1.y,
                            s1.z, s1.w, s2.x, s2.y, s2.z, s2.w};
#pragma unroll
            for (int j = 0; j < 4; ++j) {
                float dx = sv[3 * j + 0] - tg[3 * j + 0];
                float dy = sv[3 * j + 1] - tg[3 * j + 1];
                float dz = sv[3 * j + 2] - tg[3 * j + 2];
                acc[k] += (dx * dx + dy * dy + dz * dz) * inv[j];
            }
        }
    } else if (n0 < N) {
        for (int n = n0; n < N; ++n) {
            const int j = n - n0;
            float tx = xt[(size_t)n * 3 + 0];
            float ty = xt[(size_t)n * 3 + 1];
            float tz = xt[(size_t)n * 3 + 2];
#pragma unroll
            for (int k = 0; k < K; ++k) {
                const float* s = sx + (size_t)k * N * 3 + (size_t)n * 3;
                float dx = s[0] - tx, dy = s[1] - ty, dz = s[2] - tz;
                acc[k] += (dx * dx + dy * dy + dz * dz) * inv[j];
            }
        }
    }

    // ---- deterministic block reduce (shuffle + LDS) ----
#pragma unroll
    for (int k = 0; k < K; ++k)
#pragma unroll
        for (int off = 32; off > 0; off >>= 1)
            acc[k] += __shfl_down(acc[k], off, 64);
#pragma unroll
    for (int off = 32; off > 0; off >>= 1) nb += __shfl_down(nb, off, 64);

    __shared__ float lds[NW][K];
    __shared__ int   bl[NW];
    if (lane == 0) {
        bl[wave] = nb;
#pragma unroll
        for (int k = 0; k < K; ++k) lds[wave][k] = acc[k];
    }
    __syncthreads();

    // ---- cross-block accumulation: int64 fixed-point atomics (wave 0) ----
    if (tid < K) {
        float s = 0.0f;
#pragma unroll
        for (int v = 0; v < NW; ++v) s += lds[v][tid];
        unsigned long long q = (unsigned long long)llrintf(s * SCALE);
        unsigned long long old = atomicAdd(&cells[tid], q);
        asm volatile("" :: "v"(old));  // consume return -> add completed
    }
    if (tid == 0) {
        int sb = 0;
#pragma unroll
        for (int v = 0; v < NW; ++v) sb += bl[v];
        int oldv = atomicAdd(vcount, sb);
        asm volatile("" :: "v"(oldv));
    }
    // Belt-and-suspenders: all partial atomics complete before counter bump.
    asm volatile("s_waitcnt vmcnt(0)" ::: "memory");

    if (tid == 0) {
        unsigned t = atomicAdd(ctr, 1u);
        if (t == (unsigned)nblocks - 1u) {
            // Last block: coherent read-back of integer sums; finish scalar.
            long long c[K];
#pragma unroll
            for (int k = 0; k < K; ++k)
                c[k] = (long long)atomicAdd(&cells[k], 0ULL);
            int V = atomicAdd(vcount, 0);

            float wgt[K], wsum = 0.0f, g = 1.0f;
            for (int j = 0; j < K; ++j) {  // wgt[K-1-j] = GAMMA^j
                wgt[K - 1 - j] = g;
                wsum += g;
                g *= GAMMA;
            }
            float invV = (V > 0) ? 1.0f / (float)V : 0.0f;
            float res = 0.0f;
#pragma unroll
            for (int k = 0; k < K; ++k) {
                float ps = (float)c[k] * INV_SCALE * invV;
                res += (wgt[k] / wsum) * ps;
            }
            out[0] = res;
        }
    }
}

extern "C" void kernel_launch(void* const* d_in, const int* in_sizes, int n_in,
                              void* d_out, int out_size, void* d_ws, size_t ws_size,
                              hipStream_t stream) {
    const float* states_x = (const float*)d_in[0];  // (K, N, 3)
    const float* x_target = (const float*)d_in[1];  // (N, 3)
    const int*   mol      = (const int*)d_in[2];    // (N,)

    const int N = in_sizes[2];
    const int nblocks = (N + P - 1) / P;

    char* ws = (char*)d_ws;
    unsigned long long* cells = (unsigned long long*)ws;   // 64 B
    int*      vcount = (int*)(ws + 64);
    unsigned* ctr    = (unsigned*)(ws + 68);

    hipMemsetAsync(d_ws, 0, 128, stream);

    main_fused<<<nblocks, B, 0, stream>>>(states_x, x_target, mol,
                                          cells, vcount, ctr,
                                          (float*)d_out, N, nblocks);
}

// Round 13
// 49.920 us; speedup vs baseline: 1.1912x; 1.1912x over previous
//
#include <hip/hip_runtime.h>

#define GAMMA 0.7f
static constexpr int K = 8;
static constexpr int B = 512;       // threads per block
static constexpr int P = B * 4;     // atoms per block (4 per thread)
static constexpr int NW = B / 64;   // waves per block

// ---------------------------------------------------------------------------
// 2-launch pipeline (R10 champion, 50.4 us). molecule_id is SORTED. Per-atom
// molecule counts come from the block's LDS window (11-step LDS binary
// search). Runs crossing a block edge are resolved by exactly TWO global
// searches per block (thread 0 -> left run's global start, last thread ->
// right run's global end), overlapped with everyone's local searches.
// Lessons baked in:
//  R2: no per-block device fences (4x regression);
//  R8: keep 4 atoms/thread -> VGPR ~52 -> 8 waves/SIMD;
//  R11: prologue latency attacks are neutral (already TLP-hidden);
//  R12: per-block atomic+drain epilogue costs more than a 2nd launch.
// ws: [0, nblocks*K*4) partials | [boff, +nblocks*4) bcounts, both fully
// overwritten every call.
// ---------------------------------------------------------------------------

__global__ void __launch_bounds__(B)
main_fused(const float* __restrict__ sx,      // (K, N, 3)
           const float* __restrict__ xt,      // (N, 3)
           const int* __restrict__ mol,       // (N,) sorted
           float* __restrict__ partials,      // (nblocks, K)
           int* __restrict__ bcounts,         // (nblocks,)
           int N) {
    const int tid = threadIdx.x;
    const int b0  = blockIdx.x * P;
    const int n0  = b0 + tid * 4;

    // ids[0] = mol[b0-1] (or -1), ids[1..P] = window (INT_MAX past N),
    // ids[P+1] = mol[b0+P] (or INT_MAX). Real ids are in [0, M).
    __shared__ int ids[P + 2];
    __shared__ int edgeLR[2];
    int* w = ids + 1;

    int myid[4];
    if (n0 + 3 < N) {
        int4 v = *reinterpret_cast<const int4*>(mol + n0);
        myid[0] = v.x; myid[1] = v.y; myid[2] = v.z; myid[3] = v.w;
    } else {
#pragma unroll
        for (int j = 0; j < 4; ++j) {
            int n = n0 + j;
            myid[j] = (n < N) ? mol[n] : 0x7fffffff;
        }
    }
#pragma unroll
    for (int j = 0; j < 4; ++j) w[tid * 4 + j] = myid[j];
    if (tid == 0) {
        ids[0]    = (b0 == 0) ? -1 : mol[b0 - 1];
        edgeLR[0] = b0;
        edgeLR[1] = b0 + P;
    }
    if (tid == B - 1) ids[P + 1] = (b0 + P >= N) ? 0x7fffffff : mol[b0 + P];
    __syncthreads();

    // ---- two block-edge global searches, overlapped with local searches ----
    if (tid == 0 && b0 > 0 && ids[0] == w[0]) {
        const int id = w[0];  // run extends left; mol[b0-1]==id
        int hi = b0 - 1, step = 1, lo = hi - 1;
        while (lo >= 0 && mol[lo] == id) { hi = lo; step <<= 1; lo = hi - step; }
        int l2 = lo + 1;
        while (l2 < hi) { int m = (l2 + hi) >> 1; if (mol[m] < id) l2 = m + 1; else hi = m; }
        edgeLR[0] = l2;
    }
    if (tid == B - 1 && b0 + P < N && ids[P + 1] == w[P - 1]) {
        const int id = w[P - 1];  // run extends right; mol[b0+P]==id
        int lo = b0 + P, step = 1, probe = lo + step;
        while (probe < N && mol[probe] == id) { lo = probe; step <<= 1; probe = lo + step; }
        int hi = (probe < N) ? probe : N;
        int l2 = lo + 1;
        while (l2 < hi) { int m = (l2 + hi) >> 1; if (mol[m] <= id) l2 = m + 1; else hi = m; }
        edgeLR[1] = l2;
    }

    // ---- local run extents from LDS window; run-start (validity) count ----
    int sj[4], ej[4];
    int nb = 0;
#pragma unroll
    for (int j = 0; j < 4; ++j) {
        const int p  = tid * 4 + j;
        const int id = myid[j];
        const bool valid = (b0 + p < N);
        const int prevv = (j > 0) ? myid[j - 1] : ids[p];  // ids[p] == w[p-1]
        if (valid && prevv != id) ++nb;
        if (j > 0 && myid[j - 1] == id) { sj[j] = sj[j - 1]; ej[j] = ej[j - 1]; continue; }
        if (!valid) { sj[j] = 0; ej[j] = 1; continue; }  // dummy, inv unused

        int lo = 0, hi = p;
        while (lo < hi) { int m = (lo + hi) >> 1; if (w[m] < id) lo = m + 1; else hi = m; }
        sj[j] = lo;
        lo = p + 1; hi = P;
        while (lo < hi) { int m = (lo + hi) >> 1; if (w[m] <= id) lo = m + 1; else hi = m; }
        ej[j] = lo;
    }
    __syncthreads();  // edgeLR ready

    const int eL = edgeLR[0], eR = edgeLR[1];
    float inv[4];
#pragma unroll
    for (int j = 0; j < 4; ++j) {
        const bool valid = (b0 + tid * 4 + j < N);
        const int gstart = (sj[j] == 0) ? eL : b0 + sj[j];
        const int gend   = (ej[j] == P) ? eR : b0 + ej[j];
        inv[j] = valid ? 1.0f / (float)(gend - gstart) : 0.0f;
    }

    // ---- stream states, accumulate sq * inv (known-good 4-atom body) ----
    float acc[K];
#pragma unroll
    for (int k = 0; k < K; ++k) acc[k] = 0.0f;

    if (n0 + 3 < N) {
        const float4* tp = reinterpret_cast<const float4*>(xt + (size_t)n0 * 3);
        float4 t0 = tp[0], t1 = tp[1], t2 = tp[2];
        float tg[12] = {t0.x, t0.y, t0.z, t0.w, t1.x, t1.y,
                        t1.z, t1.w, t2.x, t2.y, t2.z, t2.w};
#pragma unroll
        for (int k = 0; k < K; ++k) {
            const float4* sp = reinterpret_cast<const float4*>(
                sx + (size_t)k * N * 3 + (size_t)n0 * 3);
            float4 s0 = sp[0], s1 = sp[1], s2 = sp[2];
            float sv[12] = {s0.x, s0.y, s0.z, s0.w, s1.x, s1.y,
                            s1.z, s1.w, s2.x, s2.y, s2.z, s2.w};
#pragma unroll
            for (int j = 0; j < 4; ++j) {
                float dx = sv[3 * j + 0] - tg[3 * j + 0];
                float dy = sv[3 * j + 1] - tg[3 * j + 1];
                float dz = sv[3 * j + 2] - tg[3 * j + 2];
                acc[k] += (dx * dx + dy * dy + dz * dz) * inv[j];
            }
        }
    } else if (n0 < N) {
        for (int n = n0; n < N; ++n) {
            const int j = n - n0;
            float tx = xt[(size_t)n * 3 + 0];
            float ty = xt[(size_t)n * 3 + 1];
            float tz = xt[(size_t)n * 3 + 2];
#pragma unroll
            for (int k = 0; k < K; ++k) {
                const float* s = sx + (size_t)k * N * 3 + (size_t)n * 3;
                float dx = s[0] - tx, dy = s[1] - ty, dz = s[2] - tz;
                acc[k] += (dx * dx + dy * dy + dz * dz) * inv[j];
            }
        }
    }

    // ---- deterministic block reduce (shuffle + LDS), write partials ----
#pragma unroll
    for (int k = 0; k < K; ++k)
#pragma unroll
        for (int off = 32; off > 0; off >>= 1)
            acc[k] += __shfl_down(acc[k], off, 64);
#pragma unroll
    for (int off = 32; off > 0; off >>= 1) nb += __shfl_down(nb, off, 64);

    __shared__ float lds[NW][K];
    __shared__ int   bl[NW];
    const int wave = tid >> 6, lane = tid & 63;
    if (lane == 0) {
        bl[wave] = nb;
#pragma unroll
        for (int k = 0; k < K; ++k) lds[wave][k] = acc[k];
    }
    __syncthreads();
    if (tid < K) {
        int k = tid;
        float s = 0.0f;
#pragma unroll
        for (int v = 0; v < NW; ++v) s += lds[v][k];
        partials[(size_t)blockIdx.x * K + k] = s;
    }
    if (tid == 0) {
        int s = 0;
#pragma unroll
        for (int v = 0; v < NW; ++v) s += bl[v];
        bcounts[blockIdx.x] = s;
    }
}

// One block: reduce per-block partials (nblocks*K floats) and boundary
// counts (nblocks ints). No M-sized scan.
__global__ void __launch_bounds__(B)
final_kernel(const float* __restrict__ partials,
             const int* __restrict__ bcounts, int nblocks,
             float* __restrict__ out) {
    const int t = threadIdx.x;

    int vc = 0;
    for (int i = t; i < nblocks; i += B) vc += bcounts[i];
#pragma unroll
    for (int off = 32; off > 0; off >>= 1) vc += __shfl_down(vc, off, 64);

    float acc[K];
#pragma unroll
    for (int k = 0; k < K; ++k) acc[k] = 0.0f;
    for (int i = t; i < nblocks; i += B) {
        const float4* row = reinterpret_cast<const float4*>(partials + (size_t)i * K);
        float4 a = row[0], b = row[1];
        acc[0] += a.x; acc[1] += a.y; acc[2] += a.z; acc[3] += a.w;
        acc[4] += b.x; acc[5] += b.y; acc[6] += b.z; acc[7] += b.w;
    }
#pragma unroll
    for (int k = 0; k < K; ++k)
#pragma unroll
        for (int off = 32; off > 0; off >>= 1)
            acc[k] += __shfl_down(acc[k], off, 64);

    __shared__ int vlds[NW];
    __shared__ float plds[NW][K];
    const int wave = t >> 6, lane = t & 63;
    if (lane == 0) {
        vlds[wave] = vc;
#pragma unroll
        for (int k = 0; k < K; ++k) plds[wave][k] = acc[k];
    }
    __syncthreads();

    if (t == 0) {
        int V = 0;
        float ps[K];
#pragma unroll
        for (int k = 0; k < K; ++k) ps[k] = 0.0f;
#pragma unroll
        for (int v = 0; v < NW; ++v) {
            V += vlds[v];
#pragma unroll
            for (int k = 0; k < K; ++k) ps[k] += plds[v][k];
        }
        float w[K], wsum = 0.0f, g = 1.0f;
        for (int j = 0; j < K; ++j) {  // w[K-1-j] = GAMMA^j
            w[K - 1 - j] = g;
            wsum += g;
            g *= GAMMA;
        }
        float invV = (V > 0) ? 1.0f / (float)V : 0.0f;
        float res = 0.0f;
#pragma unroll
        for (int k = 0; k < K; ++k)
            res += (w[k] / wsum) * (ps[k] * invV);
        out[0] = res;
    }
}

extern "C" void kernel_launch(void* const* d_in, const int* in_sizes, int n_in,
                              void* d_out, int out_size, void* d_ws, size_t ws_size,
                              hipStream_t stream) {
    const float* states_x = (const float*)d_in[0];  // (K, N, 3)
    const float* x_target = (const float*)d_in[1];  // (N, 3)
    const int*   mol      = (const int*)d_in[2];    // (N,)

    const int N = in_sizes[2];
    const int nblocks = (N + P - 1) / P;

    char* ws = (char*)d_ws;
    size_t boff = (((size_t)nblocks * K * 4) + 255) & ~(size_t)255;

    float* partials = (float*)ws;
    int*   bcounts  = (int*)(ws + boff);

    main_fused<<<nblocks, B, 0, stream>>>(states_x, x_target, mol,
                                          partials, bcounts, N);
    final_kernel<<<1, B, 0, stream>>>(partials, bcounts, nblocks,
                                      (float*)d_out);
}